// Round 13
// baseline (109.766 us; speedup 1.0000x reference)
//
#include <hip/hip_runtime.h>
#include <hip/hip_bf16.h>

// GAT layer, N=8192 Fin=256 Fout=64.
// v12 = v11 + software-pipelined k2 inner loop:
//   - myp DOUBLE-BUFFERED per wave: PGRP(ms+1) -> buf[(ms+1)&1] issued before
//     MFMA(ms) reads buf[ms&1]  => LDS write->read distance = full iteration.
//   - pw fragment loads hoisted to iteration top (covered by PGRP VALU burst).
//   - epilogue reduced 9 barriers -> 2 (single-shot 24KB slds alias).
//   k1: Wh=h@W; s1/s2 (s2 log2e-scaled); whT packed as MFMA A-frags (hi/lo).
//   k2: grid 2048 = (qi 0..255) x (jh 0..7); 4 waves; launch_bounds(256,4)
//       (R11: tighter cap spills f32x16 accs). adj lane<->j coalesced;
//       P built coalesced -> LDS transpose (pitch-38, conflict-free).
//   k3: sums 8 octant planes, divides, ELU. No atomics, no memset.

typedef __attribute__((ext_vector_type(8))) short bf16x8;
typedef __attribute__((ext_vector_type(16))) float f32x16;

#define LOG2E 1.4426950408889634f

__device__ __forceinline__ uint pk2o(float a, float b) {
    __hip_bfloat162 h = __float22bfloat162_rn(make_float2(a, b));
    union { __hip_bfloat162 b; uint u; } c; c.b = h; return c.u;
}
__device__ __forceinline__ ushort f2bf(float x) {
    union { __hip_bfloat16 b; ushort u; } c;
    c.b = __float2bfloat16(x);
    return c.u;
}
__device__ __forceinline__ float bf2f(ushort u) {
    union { ushort u; __hip_bfloat16 b; } c;
    c.u = u;
    return __bfloat162float(c.b);
}

// ---------------- kernel 1: Wh, s1, s2*log2e, packed A-frags ----------------
__global__ __launch_bounds__(256) void k1_wh(
    const float* __restrict__ h, const float* __restrict__ W,
    const float* __restrict__ a,
    float* __restrict__ s1, float* __restrict__ s2,
    ushort* __restrict__ pw_hi, ushort* __restrict__ pw_lo)
{
    __shared__ ushort whh[16][64], whl[16][64];
    const int l = threadIdx.x & 63;      // lane = output feature
    const int w = threadIdx.x >> 6;
    const int b = blockIdx.x;
    const int row0 = b * 16 + w * 4;

    float acc[4] = {0.f, 0.f, 0.f, 0.f};
    for (int k = 0; k < 256; k += 4) {
        float w0 = W[(k + 0) * 64 + l];
        float w1 = W[(k + 1) * 64 + l];
        float w2 = W[(k + 2) * 64 + l];
        float w3 = W[(k + 3) * 64 + l];
#pragma unroll
        for (int r = 0; r < 4; ++r) {
            const float4 hv = *reinterpret_cast<const float4*>(&h[(row0 + r) * 256 + k]);
            acc[r] = fmaf(hv.x, w0, acc[r]);
            acc[r] = fmaf(hv.y, w1, acc[r]);
            acc[r] = fmaf(hv.z, w2, acc[r]);
            acc[r] = fmaf(hv.w, w3, acc[r]);
        }
    }
    const float a1 = a[l];
    const float a2 = a[64 + l];
#pragma unroll
    for (int r = 0; r < 4; ++r) {
        const int row = row0 + r;
        float x1 = acc[r] * a1;
        float x2 = acc[r] * a2;
#pragma unroll
        for (int m = 32; m >= 1; m >>= 1) {
            x1 += __shfl_xor(x1, m);
            x2 += __shfl_xor(x2, m);
        }
        if (l == 0) { s1[row] = x1; s2[row] = x2 * LOG2E; }
        const ushort hi = f2bf(acc[r]);
        const ushort lo = f2bf(acc[r] - bf2f(hi));
        whh[w * 4 + r][l] = hi;
        whl[w * 4 + r][l] = lo;
    }
    __syncthreads();
    // PW[jstep=b][ft][lane l] = wh[(l>>5)*8+e][ft*32+(l&31)], e=0..7
    const int ft = w & 1;
    const ushort (*src)[64] = (w < 2) ? whh : whl;
    ushort* dst = (w < 2) ? pw_hi : pw_lo;
    const int hh = l >> 5;
    union { bf16x8 v; ushort s[8]; } fr;
#pragma unroll
    for (int e = 0; e < 8; ++e)
        fr.s[e] = src[hh * 8 + e][ft * 32 + (l & 31)];
    *reinterpret_cast<bf16x8*>(&dst[(size_t)(b * 2 + ft) * 512 + l * 8]) = fr.v;
}

// ---------------- kernel 2: pipelined coalesced fused attention ----------------

#define PGRP(MB, G, AV, SV, RS) { \
    float t1_, t2_, p0_, p1_, p2_, p3_; \
    t1_ = Ag[G] + (SV).x; t2_ = fmaf(0.2f, (SV).x, A5g[G]); \
    p0_ = __builtin_amdgcn_exp2f(fmaxf(t1_, t2_)); if ((AV).x <= 0) p0_ = 0.f; \
    t1_ = Ag[G] + (SV).y; t2_ = fmaf(0.2f, (SV).y, A5g[G]); \
    p1_ = __builtin_amdgcn_exp2f(fmaxf(t1_, t2_)); if ((AV).y <= 0) p1_ = 0.f; \
    t1_ = Ag[G] + (SV).z; t2_ = fmaf(0.2f, (SV).z, A5g[G]); \
    p2_ = __builtin_amdgcn_exp2f(fmaxf(t1_, t2_)); if ((AV).z <= 0) p2_ = 0.f; \
    t1_ = Ag[G] + (SV).w; t2_ = fmaf(0.2f, (SV).w, A5g[G]); \
    p3_ = __builtin_amdgcn_exp2f(fmaxf(t1_, t2_)); if ((AV).w <= 0) p3_ = 0.f; \
    RS += (p0_ + p1_) + (p2_ + p3_); \
    *reinterpret_cast<uint2*>(&(MB)[(8 * (G) + g8) * 38 + jc]) = \
        make_uint2(pk2o(p0_, p1_), pk2o(p2_, p3_)); \
}

__global__ __launch_bounds__(256, 4) void k2_attn(
    const int* __restrict__ adj,
    const float* __restrict__ s1g, const float* __restrict__ s2g,
    const ushort* __restrict__ pw_hi, const ushort* __restrict__ pw_lo,
    float* __restrict__ pacc8, float* __restrict__ pden8)
{
    // [0,4096) s2l | [4096, 4096+4*4864) myp (dbl-buf, pitch 38) | epilogue
    // aliases [0,24576) as slds[3][2][64][16]; dlds at [24576,25088).
    __shared__ __align__(16) unsigned char smem[25088];

    const int t   = threadIdx.x;
    const int l   = t & 63;
    const int wv  = t >> 6;
    const int qi  = blockIdx.x >> 3;
    const int jh  = blockIdx.x & 7;
    const int i0  = qi * 32;
    const int row = l & 31;           // B-frag row (MFMA role)
    const int kh  = l >> 5;           // k-half (MFMA role)
    const int g8  = l >> 3;           // row-in-octet (P role)
    const int jc  = (l & 7) * 4;      // j-offset (P role)

    float*  s2l  = reinterpret_cast<float*>(smem);
    ushort* mypb = reinterpret_cast<ushort*>(smem + 4096) + wv * 2432;  // 2 bufs x 1216
    float (*dlds)[32] = reinterpret_cast<float(*)[32]>(smem + 24576);

    // stage s2 octant (1024 floats, coalesced)
    reinterpret_cast<float4*>(s2l)[t] =
        reinterpret_cast<const float4*>(s2g + jh * 1024)[t];

    float Ag[4], A5g[4];
#pragma unroll
    for (int g = 0; g < 4; ++g) {
        const float s1v = s1g[i0 + 8 * g + g8];
        const float mq  = s1v + 16.0f;
        const float m   = fmaxf(mq, 0.2f * mq);
        Ag[g]  = (s1v - m) * LOG2E;
        A5g[g] = fmaf(0.2f, s1v, -m) * LOG2E;
    }
    __syncthreads();

    const int jb  = jh * 1024 + wv * 256;
    const int js0 = jb >> 4;
    const int* ap0 = adj + (size_t)(i0 + g8) * 8192 + jb + jc;
    const int* ap1 = ap0 + (size_t)8 * 8192;
    const int* ap2 = ap0 + (size_t)16 * 8192;
    const int* ap3 = ap0 + (size_t)24 * 8192;

    f32x16 acc0 = {0.f,0.f,0.f,0.f,0.f,0.f,0.f,0.f,0.f,0.f,0.f,0.f,0.f,0.f,0.f,0.f};
    f32x16 acc1 = {0.f,0.f,0.f,0.f,0.f,0.f,0.f,0.f,0.f,0.f,0.f,0.f,0.f,0.f,0.f,0.f};
    float rs0 = 0.f, rs1 = 0.f, rs2 = 0.f, rs3 = 0.f;

    // ---- prologue: PGRP(0) into buf0; adj[1] in flight ----
    int4 c0 = *reinterpret_cast<const int4*>(ap0);
    int4 c1 = *reinterpret_cast<const int4*>(ap1);
    int4 c2 = *reinterpret_cast<const int4*>(ap2);
    int4 c3 = *reinterpret_cast<const int4*>(ap3);
    int4 n0 = *reinterpret_cast<const int4*>(ap0 + 32);
    int4 n1 = *reinterpret_cast<const int4*>(ap1 + 32);
    int4 n2 = *reinterpret_cast<const int4*>(ap2 + 32);
    int4 n3 = *reinterpret_cast<const int4*>(ap3 + 32);
    {
        const float4 sv = *reinterpret_cast<const float4*>(&s2l[wv * 256 + jc]);
        PGRP(mypb, 0, c0, sv, rs0)
        PGRP(mypb, 1, c1, sv, rs1)
        PGRP(mypb, 2, c2, sv, rs2)
        PGRP(mypb, 3, c3, sv, rs3)
    }

#pragma unroll
    for (int ms = 0; ms < 8; ++ms) {
        // pw fragment loads for ms (consumed after PGRP(ms+1))
        const size_t jsA = (size_t)(js0 + ms * 2);
        const bf16x8 a0h0 = *reinterpret_cast<const bf16x8*>(&pw_hi[(jsA * 2 + 0) * 512 + l * 8]);
        const bf16x8 a0l0 = *reinterpret_cast<const bf16x8*>(&pw_lo[(jsA * 2 + 0) * 512 + l * 8]);
        const bf16x8 a0h1 = *reinterpret_cast<const bf16x8*>(&pw_hi[(jsA * 2 + 1) * 512 + l * 8]);
        const bf16x8 a0l1 = *reinterpret_cast<const bf16x8*>(&pw_lo[(jsA * 2 + 1) * 512 + l * 8]);
        const bf16x8 a1h0 = *reinterpret_cast<const bf16x8*>(&pw_hi[(jsA * 2 + 2) * 512 + l * 8]);
        const bf16x8 a1l0 = *reinterpret_cast<const bf16x8*>(&pw_lo[(jsA * 2 + 2) * 512 + l * 8]);
        const bf16x8 a1h1 = *reinterpret_cast<const bf16x8*>(&pw_hi[(jsA * 2 + 3) * 512 + l * 8]);
        const bf16x8 a1l1 = *reinterpret_cast<const bf16x8*>(&pw_lo[(jsA * 2 + 3) * 512 + l * 8]);

        if (ms < 7) {
            // PGRP(ms+1) into the other buffer; adj[ms+2] load issued first
            const int4 u0 = n0, u1 = n1, u2 = n2, u3 = n3;
            if (ms < 6) {
                const int nm = (ms + 2) * 32;
                n0 = *reinterpret_cast<const int4*>(ap0 + nm);
                n1 = *reinterpret_cast<const int4*>(ap1 + nm);
                n2 = *reinterpret_cast<const int4*>(ap2 + nm);
                n3 = *reinterpret_cast<const int4*>(ap3 + nm);
            }
            const float4 sv = *reinterpret_cast<const float4*>(&s2l[wv * 256 + (ms + 1) * 32 + jc]);
            ushort* mbW = mypb + ((ms + 1) & 1) * 1216;
            PGRP(mbW, 0, u0, sv, rs0)
            PGRP(mbW, 1, u1, sv, rs1)
            PGRP(mbW, 2, u2, sv, rs2)
            PGRP(mbW, 3, u3, sv, rs3)
        }

        // MFMA(ms) from buf[ms&1] (written LAST iteration -> latency hidden)
        const ushort* mbR = mypb + (ms & 1) * 1216;
        union { bf16x8 v; ushort4 q[2]; } b0, b1;
        b0.q[0] = *reinterpret_cast<const ushort4*>(&mbR[row * 38 + kh * 8]);
        b0.q[1] = *reinterpret_cast<const ushort4*>(&mbR[row * 38 + kh * 8 + 4]);
        b1.q[0] = *reinterpret_cast<const ushort4*>(&mbR[row * 38 + 16 + kh * 8]);
        b1.q[1] = *reinterpret_cast<const ushort4*>(&mbR[row * 38 + 16 + kh * 8 + 4]);
        acc0 = __builtin_amdgcn_mfma_f32_32x32x16_bf16(a0h0, b0.v, acc0, 0, 0, 0);
        acc0 = __builtin_amdgcn_mfma_f32_32x32x16_bf16(a0l0, b0.v, acc0, 0, 0, 0);
        acc1 = __builtin_amdgcn_mfma_f32_32x32x16_bf16(a0h1, b0.v, acc1, 0, 0, 0);
        acc1 = __builtin_amdgcn_mfma_f32_32x32x16_bf16(a0l1, b0.v, acc1, 0, 0, 0);
        acc0 = __builtin_amdgcn_mfma_f32_32x32x16_bf16(a1h0, b1.v, acc0, 0, 0, 0);
        acc0 = __builtin_amdgcn_mfma_f32_32x32x16_bf16(a1l0, b1.v, acc0, 0, 0, 0);
        acc1 = __builtin_amdgcn_mfma_f32_32x32x16_bf16(a1h1, b1.v, acc1, 0, 0, 0);
        acc1 = __builtin_amdgcn_mfma_f32_32x32x16_bf16(a1l1, b1.v, acc1, 0, 0, 0);
    }

    // ---- denominators ----
#define RED8(RS) RS += __shfl_xor(RS, 1); RS += __shfl_xor(RS, 2); RS += __shfl_xor(RS, 4);
    RED8(rs0) RED8(rs1) RED8(rs2) RED8(rs3)
    if ((l & 7) == 0) {
        dlds[wv][g8]      = rs0;
        dlds[wv][8 + g8]  = rs1;
        dlds[wv][16 + g8] = rs2;
        dlds[wv][24 + g8] = rs3;
    }
    __syncthreads();   // all waves done: myp/s2l retired, dlds ready

    // ---- single-shot cross-wave reduce (slds aliases [0,24576)) ----
    float* slds = reinterpret_cast<float*>(smem);     // [3][2][64][16]
    if (wv != 0) {
        float4* d0 = reinterpret_cast<float4*>(&slds[(((wv - 1) * 2 + 0) * 64 + l) * 16]);
        float4* d1 = reinterpret_cast<float4*>(&slds[(((wv - 1) * 2 + 1) * 64 + l) * 16]);
#pragma unroll
        for (int g = 0; g < 4; ++g) {
            d0[g] = make_float4(acc0[g*4+0], acc0[g*4+1], acc0[g*4+2], acc0[g*4+3]);
            d1[g] = make_float4(acc1[g*4+0], acc1[g*4+1], acc1[g*4+2], acc1[g*4+3]);
        }
    }
    if (wv == 0 && l < 32)
        pden8[(size_t)jh * 8192 + i0 + l] =
            dlds[0][l] + dlds[1][l] + dlds[2][l] + dlds[3][l];
    __syncthreads();

    if (wv == 0) {
#pragma unroll
        for (int s = 0; s < 3; ++s) {
            const float4* s0 = reinterpret_cast<const float4*>(&slds[((s * 2 + 0) * 64 + l) * 16]);
            const float4* s1p = reinterpret_cast<const float4*>(&slds[((s * 2 + 1) * 64 + l) * 16]);
#pragma unroll
            for (int g = 0; g < 4; ++g) {
                const float4 v0 = s0[g], v1 = s1p[g];
                acc0[g*4+0] += v0.x; acc0[g*4+1] += v0.y; acc0[g*4+2] += v0.z; acc0[g*4+3] += v0.w;
                acc1[g*4+0] += v1.x; acc1[g*4+1] += v1.y; acc1[g*4+2] += v1.z; acc1[g*4+3] += v1.w;
            }
        }
        // D layout (32x32): col=l&31 -> node row; feat-in-half = j + 8g + 4kh
        float* pb = pacc8 + ((size_t)jh * 8192 + i0 + row) * 64;
#pragma unroll
        for (int g = 0; g < 4; ++g) {
            *reinterpret_cast<float4*>(pb + 8 * g + 4 * kh) =
                make_float4(acc0[g*4+0], acc0[g*4+1], acc0[g*4+2], acc0[g*4+3]);
            *reinterpret_cast<float4*>(pb + 32 + 8 * g + 4 * kh) =
                make_float4(acc1[g*4+0], acc1[g*4+1], acc1[g*4+2], acc1[g*4+3]);
        }
    }
}

// ---------------- kernel 3: sum 8 octant planes, divide, ELU ----------------
__global__ __launch_bounds__(256) void k3_fin(
    const float* __restrict__ pacc8, const float* __restrict__ pden8,
    float* __restrict__ out)
{
    const int idx = blockIdx.x * 256 + threadIdx.x;   // 131072 float4-groups
    const int row = idx >> 4;
    float den = 0.f;
    float4 v = make_float4(0.f, 0.f, 0.f, 0.f);
#pragma unroll
    for (int p = 0; p < 8; ++p) {
        den += pden8[p * 8192 + row];
        const float4 u = reinterpret_cast<const float4*>(pacc8 + (size_t)p * 524288)[idx];
        v.x += u.x; v.y += u.y; v.z += u.z; v.w += u.w;
    }
    const float inv = 1.0f / den;
    float4 o; float x;
    x = v.x * inv; o.x = (x > 0.f) ? x : expm1f(x);
    x = v.y * inv; o.y = (x > 0.f) ? x : expm1f(x);
    x = v.z * inv; o.z = (x > 0.f) ? x : expm1f(x);
    x = v.w * inv; o.w = (x > 0.f) ? x : expm1f(x);
    reinterpret_cast<float4*>(out)[idx] = o;
}

extern "C" void kernel_launch(void* const* d_in, const int* in_sizes, int n_in,
                              void* d_out, int out_size, void* d_ws, size_t ws_size,
                              hipStream_t stream) {
    const float* h   = (const float*)d_in[0];
    const int*   adj = (const int*)d_in[1];
    const float* W   = (const float*)d_in[2];
    const float* a   = (const float*)d_in[3];
    float* out = (float*)d_out;

    float*  s1    = (float*)d_ws;                  // 8192 f32
    float*  s2    = s1 + 8192;                     // 8192 f32 (log2e-scaled)
    ushort* pw_hi = (ushort*)(s2 + 8192);          // 512 jsteps x 2 ft x 512 ushorts (1MB)
    ushort* pw_lo = pw_hi + 512 * 1024;            // 1MB
    float*  pacc8 = (float*)(pw_lo + 512 * 1024);  // [8][8192][64] f32 (16MB)
    float*  pden8 = pacc8 + 8 * 8192 * 64;         // [8][8192] f32

    hipLaunchKernelGGL(k1_wh, dim3(512), dim3(256), 0, stream,
                       h, W, a, s1, s2, pw_hi, pw_lo);
    hipLaunchKernelGGL(k2_attn, dim3(2048), dim3(256), 0, stream,
                       adj, s1, s2, pw_hi, pw_lo, pacc8, pden8);
    hipLaunchKernelGGL(k3_fin, dim3(512), dim3(256), 0, stream,
                       pacc8, pden8, out);
}

// Round 14
// 102.154 us; speedup vs baseline: 1.0745x; 1.0745x over previous
//
#include <hip/hip_runtime.h>
#include <hip/hip_bf16.h>

// GAT layer, N=8192 Fin=256 Fout=64.
// v13 = v11 (R12's 101us winner, v12 pipeline reverted) + factored exp:
//   exp(lrelu(s1+s2)) = max(Ea_i*F_j, Eb_i*G_j)   [lrelu=max(x,.2x), exp monotone]
//   F=2^(s2*L), G=2^(.2*s2*L) computed once in k1; Ea/Eb per-row in prologue.
//   Inner loop: 2 mul + max + cndmask + add per element, NO transcendentals
//   (v11 burned a quarter-rate v_exp per element -> VALU-bound at ~80us).
//   k2: grid 2048 = (qi 0..255) x (jh 0..7); 4 waves; launch_bounds(256,4).
//       adj lane<->j coalesced; P -> LDS transpose (pitch-38, conflict-free).
//   k3: sums 8 octant planes, divides, ELU. No atomics, no memset.

typedef __attribute__((ext_vector_type(8))) short bf16x8;
typedef __attribute__((ext_vector_type(16))) float f32x16;

#define LOG2E 1.4426950408889634f

__device__ __forceinline__ uint pk2o(float a, float b) {
    __hip_bfloat162 h = __float22bfloat162_rn(make_float2(a, b));
    union { __hip_bfloat162 b; uint u; } c; c.b = h; return c.u;
}
__device__ __forceinline__ ushort f2bf(float x) {
    union { __hip_bfloat16 b; ushort u; } c;
    c.b = __float2bfloat16(x);
    return c.u;
}
__device__ __forceinline__ float bf2f(ushort u) {
    union { ushort u; __hip_bfloat16 b; } c;
    c.u = u;
    return __bfloat162float(c.b);
}

// ---------------- kernel 1: Wh, s1, F, G, packed A-frags ----------------
__global__ __launch_bounds__(256) void k1_wh(
    const float* __restrict__ h, const float* __restrict__ W,
    const float* __restrict__ a,
    float* __restrict__ s1, float* __restrict__ Fg, float* __restrict__ Gg,
    ushort* __restrict__ pw_hi, ushort* __restrict__ pw_lo)
{
    __shared__ ushort whh[16][64], whl[16][64];
    const int l = threadIdx.x & 63;      // lane = output feature
    const int w = threadIdx.x >> 6;
    const int b = blockIdx.x;
    const int row0 = b * 16 + w * 4;

    float acc[4] = {0.f, 0.f, 0.f, 0.f};
    for (int k = 0; k < 256; k += 4) {
        float w0 = W[(k + 0) * 64 + l];
        float w1 = W[(k + 1) * 64 + l];
        float w2 = W[(k + 2) * 64 + l];
        float w3 = W[(k + 3) * 64 + l];
#pragma unroll
        for (int r = 0; r < 4; ++r) {
            const float4 hv = *reinterpret_cast<const float4*>(&h[(row0 + r) * 256 + k]);
            acc[r] = fmaf(hv.x, w0, acc[r]);
            acc[r] = fmaf(hv.y, w1, acc[r]);
            acc[r] = fmaf(hv.z, w2, acc[r]);
            acc[r] = fmaf(hv.w, w3, acc[r]);
        }
    }
    const float a1 = a[l];
    const float a2 = a[64 + l];
#pragma unroll
    for (int r = 0; r < 4; ++r) {
        const int row = row0 + r;
        float x1 = acc[r] * a1;
        float x2 = acc[r] * a2;
#pragma unroll
        for (int m = 32; m >= 1; m >>= 1) {
            x1 += __shfl_xor(x1, m);
            x2 += __shfl_xor(x2, m);
        }
        if (l == 0) {
            s1[row] = x1;
            Fg[row] = __builtin_amdgcn_exp2f(x2 * LOG2E);          // 2^(s2*L)
            Gg[row] = __builtin_amdgcn_exp2f(0.2f * x2 * LOG2E);   // 2^(.2*s2*L)
        }
        const ushort hi = f2bf(acc[r]);
        const ushort lo = f2bf(acc[r] - bf2f(hi));
        whh[w * 4 + r][l] = hi;
        whl[w * 4 + r][l] = lo;
    }
    __syncthreads();
    // PW[jstep=b][ft][lane l] = wh[(l>>5)*8+e][ft*32+(l&31)], e=0..7
    const int ft = w & 1;
    const ushort (*src)[64] = (w < 2) ? whh : whl;
    ushort* dst = (w < 2) ? pw_hi : pw_lo;
    const int hh = l >> 5;
    union { bf16x8 v; ushort s[8]; } fr;
#pragma unroll
    for (int e = 0; e < 8; ++e)
        fr.s[e] = src[hh * 8 + e][ft * 32 + (l & 31)];
    *reinterpret_cast<bf16x8*>(&dst[(size_t)(b * 2 + ft) * 512 + l * 8]) = fr.v;
}

// ---------------- kernel 2: coalesced fused attention (no-exp inner) ----------------

// p = max(Ea*F, Eb*G), adj-masked; fv/gv shared across the 4 row-groups
#define PGRP(G_, AV, RS) { \
    float p0_ = fmaxf(Ea[G_] * fv.x, Eb[G_] * gv.x); if ((AV).x <= 0) p0_ = 0.f; \
    float p1_ = fmaxf(Ea[G_] * fv.y, Eb[G_] * gv.y); if ((AV).y <= 0) p1_ = 0.f; \
    float p2_ = fmaxf(Ea[G_] * fv.z, Eb[G_] * gv.z); if ((AV).z <= 0) p2_ = 0.f; \
    float p3_ = fmaxf(Ea[G_] * fv.w, Eb[G_] * gv.w); if ((AV).w <= 0) p3_ = 0.f; \
    RS += (p0_ + p1_) + (p2_ + p3_); \
    *reinterpret_cast<uint2*>(&myp[(8 * (G_) + g8) * 38 + jc]) = \
        make_uint2(pk2o(p0_, p1_), pk2o(p2_, p3_)); \
}

__global__ __launch_bounds__(256, 4) void k2_attn(
    const int* __restrict__ adj,
    const float* __restrict__ s1g,
    const float* __restrict__ Fgl, const float* __restrict__ Ggl,
    const ushort* __restrict__ pw_hi, const ushort* __restrict__ pw_lo,
    float* __restrict__ pacc8, float* __restrict__ pden8)
{
    // [0,4096) F octant | [4096,8192) G octant | [8192,17920) myp (4 x 2432B,
    // pitch 38) | [17920,18432) dlds. Epilogue aliases [0,6144) chunked.
    __shared__ __align__(16) unsigned char smem[18432];

    const int t   = threadIdx.x;
    const int l   = t & 63;
    const int wv  = t >> 6;
    const int qi  = blockIdx.x >> 3;
    const int jh  = blockIdx.x & 7;
    const int i0  = qi * 32;
    const int row = l & 31;           // B-frag row (MFMA role)
    const int kh  = l >> 5;           // k-half (MFMA role)
    const int g8  = l >> 3;           // row-in-octet (P role)
    const int jc  = (l & 7) * 4;      // j-offset (P role)

    float*  Fl  = reinterpret_cast<float*>(smem);
    float*  Gl  = reinterpret_cast<float*>(smem + 4096);
    ushort* myp = reinterpret_cast<ushort*>(smem + 8192) + wv * 1216;
    float (*dlds)[32] = reinterpret_cast<float(*)[32]>(smem + 17920);

    // stage F,G octants (1024 floats each, coalesced)
    reinterpret_cast<float4*>(Fl)[t] =
        reinterpret_cast<const float4*>(Fgl + jh * 1024)[t];
    reinterpret_cast<float4*>(Gl)[t] =
        reinterpret_cast<const float4*>(Ggl + jh * 1024)[t];

    // per-lane row coefficients: Ea=2^((s1-m)L), Eb=2^((.2s1-m)L)
    float Ea[4], Eb[4];
#pragma unroll
    for (int g = 0; g < 4; ++g) {
        const float s1v = s1g[i0 + 8 * g + g8];
        const float mq  = s1v + 16.0f;
        const float m   = fmaxf(mq, 0.2f * mq);
        Ea[g] = __builtin_amdgcn_exp2f((s1v - m) * LOG2E);
        Eb[g] = __builtin_amdgcn_exp2f(fmaf(0.2f, s1v, -m) * LOG2E);
    }
    __syncthreads();

    const int jb  = jh * 1024 + wv * 256;
    const int js0 = jb >> 4;
    const int* ap0 = adj + (size_t)(i0 + g8) * 8192 + jb + jc;
    const int* ap1 = ap0 + (size_t)8 * 8192;
    const int* ap2 = ap0 + (size_t)16 * 8192;
    const int* ap3 = ap0 + (size_t)24 * 8192;

    f32x16 acc0 = {0.f,0.f,0.f,0.f,0.f,0.f,0.f,0.f,0.f,0.f,0.f,0.f,0.f,0.f,0.f,0.f};
    f32x16 acc1 = {0.f,0.f,0.f,0.f,0.f,0.f,0.f,0.f,0.f,0.f,0.f,0.f,0.f,0.f,0.f,0.f};
    float rs0 = 0.f, rs1 = 0.f, rs2 = 0.f, rs3 = 0.f;

    // 1-deep prefetch rotation, fully unrolled (8 ms-iters of 32 j)
    int4 c0 = *reinterpret_cast<const int4*>(ap0);
    int4 c1 = *reinterpret_cast<const int4*>(ap1);
    int4 c2 = *reinterpret_cast<const int4*>(ap2);
    int4 c3 = *reinterpret_cast<const int4*>(ap3);

#pragma unroll
    for (int ms = 0; ms < 8; ++ms) {
        const int nm = (ms < 7) ? (ms + 1) * 32 : 7 * 32;
        const int4 n0 = *reinterpret_cast<const int4*>(ap0 + nm);
        const int4 n1 = *reinterpret_cast<const int4*>(ap1 + nm);
        const int4 n2 = *reinterpret_cast<const int4*>(ap2 + nm);
        const int4 n3 = *reinterpret_cast<const int4*>(ap3 + nm);
        const float4 fv = *reinterpret_cast<const float4*>(&Fl[wv * 256 + ms * 32 + jc]);
        const float4 gv = *reinterpret_cast<const float4*>(&Gl[wv * 256 + ms * 32 + jc]);

        PGRP(0, c0, rs0)
        PGRP(1, c1, rs1)
        PGRP(2, c2, rs2)
        PGRP(3, c3, rs3)

#pragma unroll
        for (int ksx = 0; ksx < 2; ++ksx) {
            const int js = js0 + ms * 2 + ksx;
            const bf16x8 ah0 = *reinterpret_cast<const bf16x8*>(&pw_hi[(size_t)(js * 2 + 0) * 512 + l * 8]);
            const bf16x8 al0 = *reinterpret_cast<const bf16x8*>(&pw_lo[(size_t)(js * 2 + 0) * 512 + l * 8]);
            const bf16x8 ah1 = *reinterpret_cast<const bf16x8*>(&pw_hi[(size_t)(js * 2 + 1) * 512 + l * 8]);
            const bf16x8 al1 = *reinterpret_cast<const bf16x8*>(&pw_lo[(size_t)(js * 2 + 1) * 512 + l * 8]);
            union { bf16x8 v; ushort4 q[2]; } bh;
            bh.q[0] = *reinterpret_cast<const ushort4*>(&myp[row * 38 + ksx * 16 + kh * 8]);
            bh.q[1] = *reinterpret_cast<const ushort4*>(&myp[row * 38 + ksx * 16 + kh * 8 + 4]);
            acc0 = __builtin_amdgcn_mfma_f32_32x32x16_bf16(ah0, bh.v, acc0, 0, 0, 0);
            acc0 = __builtin_amdgcn_mfma_f32_32x32x16_bf16(al0, bh.v, acc0, 0, 0, 0);
            acc1 = __builtin_amdgcn_mfma_f32_32x32x16_bf16(ah1, bh.v, acc1, 0, 0, 0);
            acc1 = __builtin_amdgcn_mfma_f32_32x32x16_bf16(al1, bh.v, acc1, 0, 0, 0);
        }
        c0 = n0; c1 = n1; c2 = n2; c3 = n3;
    }

    // ---- denominators: 8-lane reduce, per-wave rows into dlds ----
#define RED8(RS) RS += __shfl_xor(RS, 1); RS += __shfl_xor(RS, 2); RS += __shfl_xor(RS, 4);
    RED8(rs0) RED8(rs1) RED8(rs2) RED8(rs3)
    if ((l & 7) == 0) {
        dlds[wv][g8]      = rs0;
        dlds[wv][8 + g8]  = rs1;
        dlds[wv][16 + g8] = rs2;
        dlds[wv][24 + g8] = rs3;
    }
    __syncthreads();   // dlds ready; also retires myp/Fl/Gl before aliasing

    if (wv == 0 && l < 32)
        pden8[(size_t)jh * 8192 + i0 + l] =
            dlds[0][l] + dlds[1][l] + dlds[2][l] + dlds[3][l];

    // ---- cross-wave acc reduce in 4 chunks of 4 floats (6 KB alias) ----
    float* sldsc = reinterpret_cast<float*>(smem);   // [3][2][64][4]
#pragma unroll
    for (int c = 0; c < 4; ++c) {
        if (wv != 0) {
            float4* d0 = reinterpret_cast<float4*>(&sldsc[(((wv - 1) * 2 + 0) * 64 + l) * 4]);
            float4* d1 = reinterpret_cast<float4*>(&sldsc[(((wv - 1) * 2 + 1) * 64 + l) * 4]);
            *d0 = make_float4(acc0[c*4+0], acc0[c*4+1], acc0[c*4+2], acc0[c*4+3]);
            *d1 = make_float4(acc1[c*4+0], acc1[c*4+1], acc1[c*4+2], acc1[c*4+3]);
        }
        __syncthreads();
        if (wv == 0) {
#pragma unroll
            for (int s = 0; s < 3; ++s) {
                const float4 v0 = *reinterpret_cast<const float4*>(&sldsc[((s * 2 + 0) * 64 + l) * 4]);
                const float4 v1 = *reinterpret_cast<const float4*>(&sldsc[((s * 2 + 1) * 64 + l) * 4]);
                acc0[c*4+0] += v0.x; acc0[c*4+1] += v0.y; acc0[c*4+2] += v0.z; acc0[c*4+3] += v0.w;
                acc1[c*4+0] += v1.x; acc1[c*4+1] += v1.y; acc1[c*4+2] += v1.z; acc1[c*4+3] += v1.w;
            }
        }
        __syncthreads();
    }

    if (wv == 0) {
        // D layout (32x32): col=l&31 -> node row; feat-in-half = j + 8g + 4kh
        float* pb = pacc8 + ((size_t)jh * 8192 + i0 + row) * 64;
#pragma unroll
        for (int g = 0; g < 4; ++g) {
            *reinterpret_cast<float4*>(pb + 8 * g + 4 * kh) =
                make_float4(acc0[g*4+0], acc0[g*4+1], acc0[g*4+2], acc0[g*4+3]);
            *reinterpret_cast<float4*>(pb + 32 + 8 * g + 4 * kh) =
                make_float4(acc1[g*4+0], acc1[g*4+1], acc1[g*4+2], acc1[g*4+3]);
        }
    }
}

// ---------------- kernel 3: sum 8 octant planes, divide, ELU ----------------
__global__ __launch_bounds__(256) void k3_fin(
    const float* __restrict__ pacc8, const float* __restrict__ pden8,
    float* __restrict__ out)
{
    const int idx = blockIdx.x * 256 + threadIdx.x;   // 131072 float4-groups
    const int row = idx >> 4;
    float den = 0.f;
    float4 v = make_float4(0.f, 0.f, 0.f, 0.f);
#pragma unroll
    for (int p = 0; p < 8; ++p) {
        den += pden8[p * 8192 + row];
        const float4 u = reinterpret_cast<const float4*>(pacc8 + (size_t)p * 524288)[idx];
        v.x += u.x; v.y += u.y; v.z += u.z; v.w += u.w;
    }
    const float inv = 1.0f / den;
    float4 o; float x;
    x = v.x * inv; o.x = (x > 0.f) ? x : expm1f(x);
    x = v.y * inv; o.y = (x > 0.f) ? x : expm1f(x);
    x = v.z * inv; o.z = (x > 0.f) ? x : expm1f(x);
    x = v.w * inv; o.w = (x > 0.f) ? x : expm1f(x);
    reinterpret_cast<float4*>(out)[idx] = o;
}

extern "C" void kernel_launch(void* const* d_in, const int* in_sizes, int n_in,
                              void* d_out, int out_size, void* d_ws, size_t ws_size,
                              hipStream_t stream) {
    const float* h   = (const float*)d_in[0];
    const int*   adj = (const int*)d_in[1];
    const float* W   = (const float*)d_in[2];
    const float* a   = (const float*)d_in[3];
    float* out = (float*)d_out;

    float*  s1    = (float*)d_ws;                  // 8192 f32
    float*  Fg    = s1 + 8192;                     // 8192 f32 = 2^(s2*L)
    float*  Gg    = Fg + 8192;                     // 8192 f32 = 2^(.2*s2*L)
    ushort* pw_hi = (ushort*)(Gg + 8192);          // 512 jsteps x 2 ft x 512 ushorts (1MB)
    ushort* pw_lo = pw_hi + 512 * 1024;            // 1MB
    float*  pacc8 = (float*)(pw_lo + 512 * 1024);  // [8][8192][64] f32 (16MB)
    float*  pden8 = pacc8 + 8 * 8192 * 64;         // [8][8192] f32

    hipLaunchKernelGGL(k1_wh, dim3(512), dim3(256), 0, stream,
                       h, W, a, s1, Fg, Gg, pw_hi, pw_lo);
    hipLaunchKernelGGL(k2_attn, dim3(2048), dim3(256), 0, stream,
                       adj, s1, Fg, Gg, pw_hi, pw_lo, pacc8, pden8);
    hipLaunchKernelGGL(k3_fin, dim3(512), dim3(256), 0, stream,
                       pacc8, pden8, out);
}